// Round 5
// baseline (93.744 us; speedup 1.0000x reference)
//
#include <hip/hip_runtime.h>
#include <math.h>

#define TI 8           // i-rows per block (= waves per block)
#define BLOCK 512      // threads per block (8 waves)
#define DIM 16         // embedding dim
#define RPT 4          // j-ranks per thread
#define JSPLIT 2       // j-chunks; JC = B/JSPLIT = 2048 = BLOCK*RPT

struct IRow { float4 z0, z1, z2, z3; float sq, ra; float pad0, pad1; }; // 80 B

// Counting sort of idx (keys in [0,N)) -> perm (positions sorted by key),
// skey (sorted keys), colstart (cumulative CSR offsets, N+1 valid entries).
__global__ __launch_bounds__(1024) void sort_kernel(
    const int* __restrict__ idx, int B, int N,
    int* __restrict__ perm, int* __restrict__ skey, int* __restrict__ colstart)
{
    extern __shared__ int hist[];        // N ints
    __shared__ int wsum[16];
    const int tid = threadIdx.x;
    const int lane = tid & 63, wid = tid >> 6;
    for (int b = tid; b < N; b += 1024) hist[b] = 0;
    __syncthreads();
    for (int j = tid; j < B; j += 1024) atomicAdd(&hist[idx[j]], 1);
    __syncthreads();
    const int PB = (N + 1023) >> 10;     // bins per thread (8 for N=8192)
    int local[8];
    int sum = 0;
    #pragma unroll
    for (int q = 0; q < 8; ++q) {
        if (q < PB) {
            int b = tid * PB + q;
            local[q] = sum;
            if (b < N) sum += hist[b];
        }
    }
    // block-wide exclusive scan of 'sum' via wave shuffles (3 barriers total)
    int v = sum;
    for (int off = 1; off < 64; off <<= 1) {
        int u = __shfl_up(v, off);
        if (lane >= off) v += u;
    }
    if (lane == 63) wsum[wid] = v;
    __syncthreads();
    if (tid < 16) {
        int t = wsum[tid];
        for (int off = 1; off < 16; off <<= 1) {
            int u = __shfl_up(t, off);
            if (lane >= off) t += u;
        }
        wsum[tid] = t;                   // inclusive wave prefix
    }
    __syncthreads();
    int base = (wid == 0) ? 0 : wsum[wid - 1];
    int excl = base + v - sum;           // exclusive prefix for this thread
    #pragma unroll
    for (int q = 0; q < 8; ++q) {
        if (q < PB) {
            int b = tid * PB + q;
            if (b < N) hist[b] = excl + local[q];
        }
    }
    __syncthreads();
    for (int b = tid; b < N; b += 1024) colstart[b] = hist[b];  // starts
    if (tid == 0) colstart[N] = B;
    __syncthreads();
    for (int j = tid; j < B; j += 1024) {
        int k = idx[j];
        int pos = atomicAdd(&hist[k], 1);
        perm[pos] = j;
        skey[pos] = k;
    }
}

// Permute z into sorted-rank order; precompute norms.
__global__ __launch_bounds__(256) void prep_kernel(
    const float* __restrict__ z, const int* __restrict__ perm, int B,
    float* __restrict__ zs, float* __restrict__ sqs, float* __restrict__ ras)
{
    int r = blockIdx.x * 256 + threadIdx.x;
    if (r >= B) return;
    int p = perm[r];
    const float4* src = reinterpret_cast<const float4*>(z + (size_t)p * DIM);
    float4* dst = reinterpret_cast<float4*>(zs + (size_t)r * DIM);
    float s = 0.f;
    #pragma unroll
    for (int q = 0; q < 4; ++q) {
        float4 v = src[q];
        dst[q] = v;
        s = fmaf(v.x, v.x, s); s = fmaf(v.y, v.y, s);
        s = fmaf(v.z, v.z, s); s = fmaf(v.w, v.w, s);
    }
    sqs[r] = s;
    float sc = fminf(fmaxf(s, 0.f), 0.99999f);
    ras[r] = 1.0f / (1.0f - sc);
}

__global__ __launch_bounds__(BLOCK, 4) void pair_kernel(
    const float* __restrict__ W, const int* __restrict__ skey,
    const int* __restrict__ cs,
    const float* __restrict__ zs, const float* __restrict__ sqs,
    const float* __restrict__ ras,
    int B, int N, int JC, double* __restrict__ partial)
{
    __shared__ float wlds[TI][2048];     // 64 KB: W by (row-slot, local j-rank)
    __shared__ IRow  irow[TI];
    __shared__ double red[BLOCK / 64][4];

    const int tid  = threadIdx.x;
    const int wid  = tid >> 6;
    const int lane = tid & 63;
    const int i0   = blockIdx.x * TI;
    const int jr0  = blockIdx.y * JC;
    const int jr1  = jr0 + JC;

    if (tid < TI) {
        const float4* zp = reinterpret_cast<const float4*>(zs + (size_t)(i0 + tid) * DIM);
        irow[tid].z0 = zp[0]; irow[tid].z1 = zp[1];
        irow[tid].z2 = zp[2]; irow[tid].z3 = zp[3];
        irow[tid].sq = sqs[i0 + tid];
        irow[tid].ra = ras[i0 + tid];
    }

    // stage: wave w owns row-slot w. Dense stride-1 W read + LDS scatter.
    const int row  = skey[i0 + wid];                 // wave-uniform
    const int cmin = skey[jr0] & ~3;                 // align for float4/int4
    const int cmax = skey[jr1 - 1];
    const float* Wrow = W + (size_t)row * (size_t)N;
    for (int c = cmin + lane * 4; c <= cmax; c += 64 * 4) {
        float4 wv = *reinterpret_cast<const float4*>(Wrow + c);
        int4  s4  = *reinterpret_cast<const int4*>(cs + c);
        int nx = __shfl_down(s4.x, 1);               // colstart[c+4] from lane+1
        if (lane == 63 || c + 4 > cmax) nx = cs[c + 4];
        float wa[4] = { wv.x, wv.y, wv.z, wv.w };
        int   sa[4] = { s4.x, s4.y, s4.z, s4.w };
        int   ea[4] = { s4.y, s4.z, s4.w, nx };
        #pragma unroll
        for (int q = 0; q < 4; ++q) {
            int r0 = sa[q] > jr0 ? sa[q] : jr0;
            int r1 = ea[q] < jr1 ? ea[q] : jr1;
            for (int r = r0; r < r1; ++r) wlds[wid][r - jr0] = wa[q];
        }
    }
    __syncthreads();

    // compute: each thread owns RPT consecutive sorted j-ranks
    const int jbase = jr0 + tid * RPT;
    float zj[RPT][DIM];
    float sqj[RPT], raj[RPT];
    {
        float4 s4 = *reinterpret_cast<const float4*>(sqs + jbase);
        float4 r4 = *reinterpret_cast<const float4*>(ras + jbase);
        sqj[0]=s4.x; sqj[1]=s4.y; sqj[2]=s4.z; sqj[3]=s4.w;
        raj[0]=r4.x; raj[1]=r4.y; raj[2]=r4.z; raj[3]=r4.w;
    }
    #pragma unroll
    for (int r = 0; r < RPT; ++r) {
        const float4* zp = reinterpret_cast<const float4*>(zs + (size_t)(jbase + r) * DIM);
        #pragma unroll
        for (int q = 0; q < 4; ++q) {
            float4 vv = zp[q];
            zj[r][4*q+0] = vv.x; zj[r][4*q+1] = vv.y;
            zj[r][4*q+2] = vv.z; zj[r][4*q+3] = vv.w;
        }
    }

    float a_wd = 0.f, a_w = 0.f, a_rep = 0.f;
    int a_cnt = 0;
    #pragma unroll
    for (int ii = 0; ii < TI; ++ii) {
        float4 w4 = *reinterpret_cast<const float4*>(&wlds[ii][tid * RPT]); // b128
        float wq[4] = { w4.x, w4.y, w4.z, w4.w };
        float4 x0 = irow[ii].z0, x1 = irow[ii].z1;
        float4 x2 = irow[ii].z2, x3 = irow[ii].z3;
        const float sqi_ = irow[ii].sq;
        const float rai_ = irow[ii].ra;
        const int   idia = i0 + ii;
        #pragma unroll
        for (int r = 0; r < RPT; ++r) {
            float dot = 0.f;
            dot = fmaf(x0.x, zj[r][0],  dot); dot = fmaf(x0.y, zj[r][1],  dot);
            dot = fmaf(x0.z, zj[r][2],  dot); dot = fmaf(x0.w, zj[r][3],  dot);
            dot = fmaf(x1.x, zj[r][4],  dot); dot = fmaf(x1.y, zj[r][5],  dot);
            dot = fmaf(x1.z, zj[r][6],  dot); dot = fmaf(x1.w, zj[r][7],  dot);
            dot = fmaf(x2.x, zj[r][8],  dot); dot = fmaf(x2.y, zj[r][9],  dot);
            dot = fmaf(x2.z, zj[r][10], dot); dot = fmaf(x2.w, zj[r][11], dot);
            dot = fmaf(x3.x, zj[r][12], dot); dot = fmaf(x3.y, zj[r][13], dot);
            dot = fmaf(x3.z, zj[r][14], dot); dot = fmaf(x3.w, zj[r][15], dot);
            float sqd = fmaxf(sqi_ + sqj[r] - 2.0f * dot, 0.0f);
            float x = fmaf(sqd * rai_ * raj[r], 2.0f, 1.0f);
            float t = __builtin_amdgcn_sqrtf(fmaxf(fmaf(x, x, -1.0f), 1e-10f));
            float d = __logf(x + t);
            float w = wq[r];
            bool diag = (idia == jbase + r);
            if (diag) w = 0.0f;
            a_wd += w * d;
            a_w  += w;
            bool rep = (w == 0.0f) && !diag;   // exp(-d) = 1/(x+t) = x - t
            a_rep += rep ? (x - t) : 0.0f;
            a_cnt += rep ? 1 : 0;
        }
    }

    double vals[4] = { (double)a_wd, (double)a_w, (double)a_rep, (double)a_cnt };
    #pragma unroll
    for (int c = 0; c < 4; ++c) {
        double v = vals[c];
        for (int off = 32; off > 0; off >>= 1) v += __shfl_down(v, off);
        vals[c] = v;
    }
    if (lane == 0) {
        #pragma unroll
        for (int c = 0; c < 4; ++c) red[wid][c] = vals[c];
    }
    __syncthreads();
    if (tid == 0) {
        double tot[4] = {0.0, 0.0, 0.0, 0.0};
        for (int wgt = 0; wgt < BLOCK / 64; ++wgt)
            for (int c = 0; c < 4; ++c) tot[c] += red[wgt][c];
        size_t bid = (size_t)blockIdx.y * gridDim.x + blockIdx.x;
        #pragma unroll
        for (int c = 0; c < 4; ++c) partial[bid * 4 + c] = tot[c];
    }
}

__global__ __launch_bounds__(1024) void finish_kernel(
    const double* __restrict__ partial, int nblocks, float* __restrict__ out)
{
    __shared__ double red[16][4];
    const int tid = threadIdx.x, wid = tid >> 6, lane = tid & 63;
    double vals[4] = {0.0, 0.0, 0.0, 0.0};
    for (int b = tid; b < nblocks; b += 1024)
        for (int c = 0; c < 4; ++c) vals[c] += partial[(size_t)b * 4 + c];
    #pragma unroll
    for (int c = 0; c < 4; ++c) {
        double v = vals[c];
        for (int off = 32; off > 0; off >>= 1) v += __shfl_down(v, off);
        vals[c] = v;
    }
    if (lane == 0)
        for (int c = 0; c < 4; ++c) red[wid][c] = vals[c];
    __syncthreads();
    if (tid == 0) {
        double tot[4] = {0.0, 0.0, 0.0, 0.0};
        for (int wgt = 0; wgt < 16; ++wgt)
            for (int c = 0; c < 4; ++c) tot[c] += red[wgt][c];
        double la = tot[0] / (tot[1] + 1e-8);
        double lr = tot[2] / (tot[3] + 1e-8);
        out[0] = (float)(la + lr);
    }
}

extern "C" void kernel_launch(void* const* d_in, const int* in_sizes, int n_in,
                              void* d_out, int out_size, void* d_ws, size_t ws_size,
                              hipStream_t stream)
{
    const float* z  = (const float*)d_in[0];
    const float* W  = (const float*)d_in[1];
    const int* idx  = (const int*)d_in[2];
    const int B = in_sizes[2];                       // 4096
    int N = 1;
    while ((long long)(N + 1) * (N + 1) <= (long long)in_sizes[1]) ++N;

    const int JC = B / JSPLIT;                       // 2048
    const int nblocks = (B / TI) * JSPLIT;           // 1024

    // workspace layout (16B-aligned sections)
    double* partial = (double*)d_ws;                 // nblocks*4 doubles
    int* perm     = (int*)(partial + (size_t)nblocks * 4);
    int* skey     = perm + B;
    int* colstart = skey + B;                        // N+1 used, pad to N+4
    float* zs     = (float*)(colstart + N + 4);      // B*DIM floats (16B-aligned)
    float* sqs    = zs + (size_t)B * DIM;
    float* ras    = sqs + B;

    sort_kernel<<<1, 1024, (size_t)N * sizeof(int), stream>>>(
        idx, B, N, perm, skey, colstart);
    prep_kernel<<<(B + 255) / 256, 256, 0, stream>>>(z, perm, B, zs, sqs, ras);

    dim3 grid(B / TI, JSPLIT);
    pair_kernel<<<grid, BLOCK, 0, stream>>>(W, skey, colstart,
                                            zs, sqs, ras, B, N, JC, partial);
    finish_kernel<<<1, 1024, 0, stream>>>(partial, nblocks, (float*)d_out);
}

// Round 6
// 75.235 us; speedup vs baseline: 1.2460x; 1.2460x over previous
//
#include <hip/hip_runtime.h>
#include <math.h>

#define TI 32          // i-rows per block
#define BLOCK 512      // 8 waves; each wave owns a 32-rank j-tile
#define DIM 16         // embedding dim
#define JC 256         // j-ranks per block = 8 waves * 32

typedef short bf16x8 __attribute__((ext_vector_type(8)));
typedef float f32x16 __attribute__((ext_vector_type(16)));

static __device__ __forceinline__ short f2bf(float f) {
    unsigned u = __builtin_bit_cast(unsigned, f);
    unsigned r = (u + 0x7FFFu + ((u >> 16) & 1u)) >> 16;   // RNE
    return (short)r;
}

// Counting sort of idx -> perm/skey sorted by key, colstart (N+1 CSR offsets).
__global__ __launch_bounds__(1024) void sort_kernel(
    const int* __restrict__ idx, int B, int N,
    int* __restrict__ perm, int* __restrict__ skey, int* __restrict__ colstart)
{
    extern __shared__ int hist[];        // N ints
    __shared__ int wsum[16];
    const int tid = threadIdx.x;
    const int lane = tid & 63, wid = tid >> 6;
    for (int b = tid; b < N; b += 1024) hist[b] = 0;
    __syncthreads();
    for (int j = tid; j < B; j += 1024) atomicAdd(&hist[idx[j]], 1);
    __syncthreads();
    const int PB = (N + 1023) >> 10;
    int local[8];
    int sum = 0;
    #pragma unroll
    for (int q = 0; q < 8; ++q) {
        if (q < PB) {
            int b = tid * PB + q;
            local[q] = sum;
            if (b < N) sum += hist[b];
        }
    }
    int v = sum;
    for (int off = 1; off < 64; off <<= 1) {
        int u = __shfl_up(v, off);
        if (lane >= off) v += u;
    }
    if (lane == 63) wsum[wid] = v;
    __syncthreads();
    if (tid < 16) {
        int t = wsum[tid];
        for (int off = 1; off < 16; off <<= 1) {
            int u = __shfl_up(t, off);
            if (lane >= off) t += u;
        }
        wsum[tid] = t;
    }
    __syncthreads();
    int base = (wid == 0) ? 0 : wsum[wid - 1];
    int excl = base + v - sum;
    #pragma unroll
    for (int q = 0; q < 8; ++q) {
        if (q < PB) {
            int b = tid * PB + q;
            if (b < N) hist[b] = excl + local[q];
        }
    }
    __syncthreads();
    for (int b = tid; b < N; b += 1024) colstart[b] = hist[b];
    if (tid == 0) colstart[N] = B;
    __syncthreads();
    for (int j = tid; j < B; j += 1024) {
        int k = idx[j];
        int pos = atomicAdd(&hist[k], 1);
        perm[pos] = j;
        skey[pos] = k;
    }
}

// Permute z into sorted order; precompute raw sq-norm and 1/(1-clamped).
__global__ __launch_bounds__(256) void prep_kernel(
    const float* __restrict__ z, const int* __restrict__ perm, int B,
    float* __restrict__ zs, float* __restrict__ sqs, float* __restrict__ ras)
{
    int r = blockIdx.x * 256 + threadIdx.x;
    if (r >= B) return;
    int p = perm[r];
    const float4* src = reinterpret_cast<const float4*>(z + (size_t)p * DIM);
    float4* dst = reinterpret_cast<float4*>(zs + (size_t)r * DIM);
    float s = 0.f;
    #pragma unroll
    for (int q = 0; q < 4; ++q) {
        float4 v = src[q];
        dst[q] = v;
        s = fmaf(v.x, v.x, s); s = fmaf(v.y, v.y, s);
        s = fmaf(v.z, v.z, s); s = fmaf(v.w, v.w, s);
    }
    sqs[r] = s;                                  // raw (for sqdist)
    float sc = fminf(fmaxf(s, 0.f), 0.99999f);   // clamped (for alpha)
    ras[r] = 1.0f / (1.0f - sc);
}

__global__ __launch_bounds__(BLOCK, 8) void pair_kernel(
    const float* __restrict__ W, const int* __restrict__ skey,
    const int* __restrict__ cs,
    const float* __restrict__ zs, const float* __restrict__ sqs,
    const float* __restrict__ ras,
    int B, int N, double* __restrict__ partial)
{
    __shared__ float wlds[TI][JC];       // 32 KB
    __shared__ double red[BLOCK / 64][4];

    const int tid  = threadIdx.x;
    const int wv   = tid >> 6;           // wave 0..7
    const int lane = tid & 63;
    const int half = lane >> 5;
    const int sub  = lane & 31;
    const int i0   = blockIdx.x * TI;
    const int jr0  = blockIdx.y * JC;
    const int jr1  = jr0 + JC;

    // ---- stage: wave wv fills row-slots 4wv..4wv+3 (dense W read + scatter) ----
    const int cmin = skey[jr0] & ~3;
    const int cmax = skey[jr1 - 1];
    #pragma unroll
    for (int q = 0; q < 4; ++q) {
        const int rs = wv * 4 + q;
        const float* Wrow = W + (size_t)skey[i0 + rs] * (size_t)N;
        for (int c = cmin + lane * 4; c <= cmax; c += 256) {
            float4 wv4 = *reinterpret_cast<const float4*>(Wrow + c);
            int4  s4   = *reinterpret_cast<const int4*>(cs + c);
            int nx = __shfl_down(s4.x, 1);
            if (lane == 63 || c + 4 > cmax) nx = cs[c + 4];
            float wa[4] = { wv4.x, wv4.y, wv4.z, wv4.w };
            int   sa[4] = { s4.x, s4.y, s4.z, s4.w };
            int   ea[4] = { s4.y, s4.z, s4.w, nx };
            #pragma unroll
            for (int t = 0; t < 4; ++t) {
                int r0 = sa[t] > jr0 ? sa[t] : jr0;
                int r1 = ea[t] < jr1 ? ea[t] : jr1;
                for (int rr = r0; rr < r1; ++rr) wlds[rs][rr - jr0] = wa[t];
            }
        }
    }

    // ---- MFMA fragments: x-1 = A1.B1 + A2.B2 (18-dim bilinear form) ----
    // A-lane: i-row = i0+sub, k = 8*half+e. B-lane: j-rank = jr0+wv*32+sub.
    const int irow  = i0 + sub;
    const int jrank = jr0 + wv * 32 + sub;
    const float ui = ras[irow],  vi = sqs[irow]  * ui;
    const float uj = ras[jrank], vj = sqs[jrank] * uj;
    bf16x8 a1, b1, a2, b2;
    {
        const float4* zp = reinterpret_cast<const float4*>(zs + (size_t)irow * DIM + 8 * half);
        float4 p0 = zp[0], p1 = zp[1];
        float s = 2.0f * ui;
        a1[0]=f2bf(s*p0.x); a1[1]=f2bf(s*p0.y); a1[2]=f2bf(s*p0.z); a1[3]=f2bf(s*p0.w);
        a1[4]=f2bf(s*p1.x); a1[5]=f2bf(s*p1.y); a1[6]=f2bf(s*p1.z); a1[7]=f2bf(s*p1.w);
    }
    {
        const float4* zp = reinterpret_cast<const float4*>(zs + (size_t)jrank * DIM + 8 * half);
        float4 p0 = zp[0], p1 = zp[1];
        float s = -2.0f * uj;
        b1[0]=f2bf(s*p0.x); b1[1]=f2bf(s*p0.y); b1[2]=f2bf(s*p0.z); b1[3]=f2bf(s*p0.w);
        b1[4]=f2bf(s*p1.x); b1[5]=f2bf(s*p1.y); b1[6]=f2bf(s*p1.z); b1[7]=f2bf(s*p1.w);
    }
    #pragma unroll
    for (int e = 0; e < 8; ++e) { a2[e] = 0; b2[e] = 0; }
    if (half == 0) {
        a2[0] = f2bf(2.0f * vi); a2[1] = f2bf(2.0f * ui);
        b2[0] = f2bf(uj);        b2[1] = f2bf(vj);
    }

    f32x16 acc = {};
    acc = __builtin_amdgcn_mfma_f32_32x32x16_bf16(a1, b1, acc, 0, 0, 0);
    acc = __builtin_amdgcn_mfma_f32_32x32x16_bf16(a2, b2, acc, 0, 0, 0);

    __syncthreads();

    // ---- epilogue: 16 pairs per thread ----
    float a_wd = 0.f, a_w = 0.f, a_rep = 0.f, a_cnt = 0.f;
    #pragma unroll
    for (int r = 0; r < 16; ++r) {
        const int row = (r & 3) + 8 * (r >> 2) + 4 * half;   // C row = i-slot
        float xm1 = fmaxf(acc[r], 0.0f);                     // sqd>=0 clamp
        float w = wlds[row][wv * 32 + sub];
        float t = __builtin_amdgcn_sqrtf(fmaxf(xm1 * (xm1 + 2.0f), 1e-10f));
        float x = xm1 + 1.0f;
        float d = __logf(x + t);             // d = log(x+sqrt(x^2-1))
        bool diag = ((i0 + row) == jrank);
        if (diag) w = 0.0f;
        a_wd += w * d;
        a_w  += w;
        bool rep = (w == 0.0f) && !diag;     // exp(-d) = 1/(x+t) = x - t
        a_rep += rep ? (x - t) : 0.0f;
        a_cnt += rep ? 1.0f : 0.0f;
    }

    double vals[4] = { (double)a_wd, (double)a_w, (double)a_rep, (double)a_cnt };
    #pragma unroll
    for (int c = 0; c < 4; ++c) {
        double v = vals[c];
        for (int off = 32; off > 0; off >>= 1) v += __shfl_down(v, off);
        vals[c] = v;
    }
    if (lane == 0) {
        #pragma unroll
        for (int c = 0; c < 4; ++c) red[wv][c] = vals[c];
    }
    __syncthreads();
    if (tid == 0) {
        double tot[4] = {0.0, 0.0, 0.0, 0.0};
        for (int wgt = 0; wgt < BLOCK / 64; ++wgt)
            for (int c = 0; c < 4; ++c) tot[c] += red[wgt][c];
        size_t bid = (size_t)blockIdx.y * gridDim.x + blockIdx.x;
        #pragma unroll
        for (int c = 0; c < 4; ++c) partial[bid * 4 + c] = tot[c];
    }
}

__global__ __launch_bounds__(1024) void finish_kernel(
    const double* __restrict__ partial, int nblocks, float* __restrict__ out)
{
    __shared__ double red[16][4];
    const int tid = threadIdx.x, wid = tid >> 6, lane = tid & 63;
    double vals[4] = {0.0, 0.0, 0.0, 0.0};
    for (int b = tid; b < nblocks; b += 1024)
        for (int c = 0; c < 4; ++c) vals[c] += partial[(size_t)b * 4 + c];
    #pragma unroll
    for (int c = 0; c < 4; ++c) {
        double v = vals[c];
        for (int off = 32; off > 0; off >>= 1) v += __shfl_down(v, off);
        vals[c] = v;
    }
    if (lane == 0)
        for (int c = 0; c < 4; ++c) red[wid][c] = vals[c];
    __syncthreads();
    if (tid == 0) {
        double tot[4] = {0.0, 0.0, 0.0, 0.0};
        for (int wgt = 0; wgt < 16; ++wgt)
            for (int c = 0; c < 4; ++c) tot[c] += red[wgt][c];
        double la = tot[0] / (tot[1] + 1e-8);
        double lr = tot[2] / (tot[3] + 1e-8);
        out[0] = (float)(la + lr);
    }
}

extern "C" void kernel_launch(void* const* d_in, const int* in_sizes, int n_in,
                              void* d_out, int out_size, void* d_ws, size_t ws_size,
                              hipStream_t stream)
{
    const float* z  = (const float*)d_in[0];
    const float* W  = (const float*)d_in[1];
    const int* idx  = (const int*)d_in[2];
    const int B = in_sizes[2];                       // 4096
    int N = 1;
    while ((long long)(N + 1) * (N + 1) <= (long long)in_sizes[1]) ++N;

    const int nblocks = (B / TI) * (B / JC);         // 128 * 16 = 2048

    // workspace layout (16B-aligned sections)
    double* partial = (double*)d_ws;                 // nblocks*4 doubles
    int* perm     = (int*)(partial + (size_t)nblocks * 4);
    int* skey     = perm + B;
    int* colstart = skey + B;                        // N+1 used, pad to N+4
    float* zs     = (float*)(colstart + N + 4);      // B*DIM floats
    float* sqs    = zs + (size_t)B * DIM;
    float* ras    = sqs + B;

    sort_kernel<<<1, 1024, (size_t)N * sizeof(int), stream>>>(
        idx, B, N, perm, skey, colstart);
    prep_kernel<<<(B + 255) / 256, 256, 0, stream>>>(z, perm, B, zs, sqs, ras);

    dim3 grid(B / TI, B / JC);
    pair_kernel<<<grid, BLOCK, 0, stream>>>(W, skey, colstart,
                                            zs, sqs, ras, B, N, partial);
    finish_kernel<<<1, 1024, 0, stream>>>(partial, nblocks, (float*)d_out);
}

// Round 7
// 42.771 us; speedup vs baseline: 2.1918x; 1.7590x over previous
//
#include <hip/hip_runtime.h>
#include <math.h>

#define TI 32          // i-rows per block
#define BLOCK 512      // 8 waves; each wave owns a 32-rank j-tile
#define DIM 16         // embedding dim
#define JC 256         // j-ranks per block = 8 waves * 32

typedef short bf16x8 __attribute__((ext_vector_type(8)));
typedef float f32x16 __attribute__((ext_vector_type(16)));

static __device__ __forceinline__ short f2bf(float f) {
    unsigned u = __builtin_bit_cast(unsigned, f);
    unsigned r = (u + 0x7FFFu + ((u >> 16) & 1u)) >> 16;   // RNE
    return (short)r;
}

// Counting sort of idx -> perm/skey sorted by key.
__global__ __launch_bounds__(1024) void sort_kernel(
    const int* __restrict__ idx, int B, int N,
    int* __restrict__ perm, int* __restrict__ skey)
{
    extern __shared__ int hist[];        // N ints
    __shared__ int wsum[16];
    const int tid = threadIdx.x;
    const int lane = tid & 63, wid = tid >> 6;
    for (int b = tid; b < N; b += 1024) hist[b] = 0;
    __syncthreads();
    for (int j = tid; j < B; j += 1024) atomicAdd(&hist[idx[j]], 1);
    __syncthreads();
    const int PB = (N + 1023) >> 10;
    int local[8];
    int sum = 0;
    #pragma unroll
    for (int q = 0; q < 8; ++q) {
        if (q < PB) {
            int b = tid * PB + q;
            local[q] = sum;
            if (b < N) sum += hist[b];
        }
    }
    int v = sum;
    for (int off = 1; off < 64; off <<= 1) {
        int u = __shfl_up(v, off);
        if (lane >= off) v += u;
    }
    if (lane == 63) wsum[wid] = v;
    __syncthreads();
    if (tid < 16) {
        int t = wsum[tid];
        for (int off = 1; off < 16; off <<= 1) {
            int u = __shfl_up(t, off);
            if (lane >= off) t += u;
        }
        wsum[tid] = t;
    }
    __syncthreads();
    int base = (wid == 0) ? 0 : wsum[wid - 1];
    int excl = base + v - sum;
    #pragma unroll
    for (int q = 0; q < 8; ++q) {
        if (q < PB) {
            int b = tid * PB + q;
            if (b < N) hist[b] = excl + local[q];
        }
    }
    __syncthreads();
    for (int j = tid; j < B; j += 1024) {
        int k = idx[j];
        int pos = atomicAdd(&hist[k], 1);
        perm[pos] = j;
        skey[pos] = k;
    }
}

// Permute z into sorted order; precompute raw sq-norm and 1/(1-clamped).
__global__ __launch_bounds__(256) void prep_kernel(
    const float* __restrict__ z, const int* __restrict__ perm, int B,
    float* __restrict__ zs, float* __restrict__ sqs, float* __restrict__ ras)
{
    int r = blockIdx.x * 256 + threadIdx.x;
    if (r >= B) return;
    int p = perm[r];
    const float4* src = reinterpret_cast<const float4*>(z + (size_t)p * DIM);
    float4* dst = reinterpret_cast<float4*>(zs + (size_t)r * DIM);
    float s = 0.f;
    #pragma unroll
    for (int q = 0; q < 4; ++q) {
        float4 v = src[q];
        dst[q] = v;
        s = fmaf(v.x, v.x, s); s = fmaf(v.y, v.y, s);
        s = fmaf(v.z, v.z, s); s = fmaf(v.w, v.w, s);
    }
    sqs[r] = s;                                  // raw (for sqdist)
    float sc = fminf(fmaxf(s, 0.f), 0.99999f);   // clamped (for alpha)
    ras[r] = 1.0f / (1.0f - sc);
}

__global__ __launch_bounds__(BLOCK, 4) void pair_kernel(
    const float* __restrict__ W, const int* __restrict__ skey,
    const float* __restrict__ zs, const float* __restrict__ sqs,
    const float* __restrict__ ras,
    int B, int N, double* __restrict__ partial)
{
    __shared__ double red[BLOCK / 64][4];

    const int tid  = threadIdx.x;
    const int wv   = tid >> 6;           // wave 0..7
    const int lane = tid & 63;
    const int half = lane >> 5;
    const int sub  = lane & 31;
    const int i0   = blockIdx.x * TI;
    const int jr0  = blockIdx.y * JC;

    const int irow  = i0 + sub;                  // A-fragment i-row
    const int jrank = jr0 + wv * 32 + sub;       // B-fragment j-rank
    const int kj    = skey[jrank];               // W column (sorted across lanes)

    // ---- direct W gather: 16 values per thread, coalesced via sorted kj ----
    float wg[16];
    #pragma unroll
    for (int r = 0; r < 16; ++r) {
        const int rowm = (r & 3) + 8 * (r >> 2) + 4 * half;   // C-fragment row
        const int skr  = skey[i0 + rowm];                      // L1-hot
        wg[r] = W[(size_t)skr * (size_t)N + (size_t)kj];
    }

    // ---- MFMA fragments: x-1 = A1.B1 + A2.B2 (18-dim bilinear form) ----
    const float ui = ras[irow],  vi = sqs[irow]  * ui;
    const float uj = ras[jrank], vj = sqs[jrank] * uj;
    bf16x8 a1, b1, a2, b2;
    {
        const float4* zp = reinterpret_cast<const float4*>(zs + (size_t)irow * DIM + 8 * half);
        float4 p0 = zp[0], p1 = zp[1];
        float s = 2.0f * ui;
        a1[0]=f2bf(s*p0.x); a1[1]=f2bf(s*p0.y); a1[2]=f2bf(s*p0.z); a1[3]=f2bf(s*p0.w);
        a1[4]=f2bf(s*p1.x); a1[5]=f2bf(s*p1.y); a1[6]=f2bf(s*p1.z); a1[7]=f2bf(s*p1.w);
    }
    {
        const float4* zp = reinterpret_cast<const float4*>(zs + (size_t)jrank * DIM + 8 * half);
        float4 p0 = zp[0], p1 = zp[1];
        float s = -2.0f * uj;
        b1[0]=f2bf(s*p0.x); b1[1]=f2bf(s*p0.y); b1[2]=f2bf(s*p0.z); b1[3]=f2bf(s*p0.w);
        b1[4]=f2bf(s*p1.x); b1[5]=f2bf(s*p1.y); b1[6]=f2bf(s*p1.z); b1[7]=f2bf(s*p1.w);
    }
    #pragma unroll
    for (int e = 0; e < 8; ++e) { a2[e] = 0; b2[e] = 0; }
    if (half == 0) {
        a2[0] = f2bf(2.0f * vi); a2[1] = f2bf(2.0f * ui);
        b2[0] = f2bf(uj);        b2[1] = f2bf(vj);
    }

    f32x16 acc = {};
    acc = __builtin_amdgcn_mfma_f32_32x32x16_bf16(a1, b1, acc, 0, 0, 0);
    acc = __builtin_amdgcn_mfma_f32_32x32x16_bf16(a2, b2, acc, 0, 0, 0);

    // ---- epilogue: 16 pairs per thread ----
    float a_wd = 0.f, a_w = 0.f, a_rep = 0.f, a_cnt = 0.f;
    #pragma unroll
    for (int r = 0; r < 16; ++r) {
        const int rowm = (r & 3) + 8 * (r >> 2) + 4 * half;
        float xm1 = fmaxf(acc[r], 0.0f);                     // sqd>=0 clamp
        float w = wg[r];
        float t = __builtin_amdgcn_sqrtf(fmaxf(xm1 * (xm1 + 2.0f), 1e-10f));
        float x = xm1 + 1.0f;
        float d = __logf(x + t);             // d = log(x+sqrt(x^2-1))
        bool diag = ((i0 + rowm) == jrank);
        if (diag) w = 0.0f;
        a_wd += w * d;
        a_w  += w;
        bool rep = (w == 0.0f) && !diag;     // exp(-d) = 1/(x+t) = x - t
        a_rep += rep ? (x - t) : 0.0f;
        a_cnt += rep ? 1.0f : 0.0f;
    }

    double vals[4] = { (double)a_wd, (double)a_w, (double)a_rep, (double)a_cnt };
    #pragma unroll
    for (int c = 0; c < 4; ++c) {
        double v = vals[c];
        for (int off = 32; off > 0; off >>= 1) v += __shfl_down(v, off);
        vals[c] = v;
    }
    if (lane == 0) {
        #pragma unroll
        for (int c = 0; c < 4; ++c) red[wv][c] = vals[c];
    }
    __syncthreads();
    if (tid == 0) {
        double tot[4] = {0.0, 0.0, 0.0, 0.0};
        for (int wgt = 0; wgt < BLOCK / 64; ++wgt)
            for (int c = 0; c < 4; ++c) tot[c] += red[wgt][c];
        size_t bid = (size_t)blockIdx.y * gridDim.x + blockIdx.x;
        #pragma unroll
        for (int c = 0; c < 4; ++c) partial[bid * 4 + c] = tot[c];
    }
}

__global__ __launch_bounds__(1024) void finish_kernel(
    const double* __restrict__ partial, int nblocks, float* __restrict__ out)
{
    __shared__ double red[16][4];
    const int tid = threadIdx.x, wid = tid >> 6, lane = tid & 63;
    double vals[4] = {0.0, 0.0, 0.0, 0.0};
    for (int b = tid; b < nblocks; b += 1024)
        for (int c = 0; c < 4; ++c) vals[c] += partial[(size_t)b * 4 + c];
    #pragma unroll
    for (int c = 0; c < 4; ++c) {
        double v = vals[c];
        for (int off = 32; off > 0; off >>= 1) v += __shfl_down(v, off);
        vals[c] = v;
    }
    if (lane == 0)
        for (int c = 0; c < 4; ++c) red[wid][c] = vals[c];
    __syncthreads();
    if (tid == 0) {
        double tot[4] = {0.0, 0.0, 0.0, 0.0};
        for (int wgt = 0; wgt < 16; ++wgt)
            for (int c = 0; c < 4; ++c) tot[c] += red[wgt][c];
        double la = tot[0] / (tot[1] + 1e-8);
        double lr = tot[2] / (tot[3] + 1e-8);
        out[0] = (float)(la + lr);
    }
}

extern "C" void kernel_launch(void* const* d_in, const int* in_sizes, int n_in,
                              void* d_out, int out_size, void* d_ws, size_t ws_size,
                              hipStream_t stream)
{
    const float* z  = (const float*)d_in[0];
    const float* W  = (const float*)d_in[1];
    const int* idx  = (const int*)d_in[2];
    const int B = in_sizes[2];                       // 4096
    int N = 1;
    while ((long long)(N + 1) * (N + 1) <= (long long)in_sizes[1]) ++N;

    const int nblocks = (B / TI) * (B / JC);         // 128 * 16 = 2048

    // workspace layout (16B-aligned sections)
    double* partial = (double*)d_ws;                 // nblocks*4 doubles
    int* perm     = (int*)(partial + (size_t)nblocks * 4);
    int* skey     = perm + B;
    float* zs     = (float*)(skey + B);              // B*DIM floats
    float* sqs    = zs + (size_t)B * DIM;
    float* ras    = sqs + B;

    sort_kernel<<<1, 1024, (size_t)N * sizeof(int), stream>>>(idx, B, N, perm, skey);
    prep_kernel<<<(B + 255) / 256, 256, 0, stream>>>(z, perm, B, zs, sqs, ras);

    dim3 grid(B / TI, B / JC);
    pair_kernel<<<grid, BLOCK, 0, stream>>>(W, skey, zs, sqs, ras, B, N, partial);
    finish_kernel<<<1, 1024, 0, stream>>>(partial, nblocks, (float*)d_out);
}